// Round 1
// baseline (476.511 us; speedup 1.0000x reference)
//
#include <hip/hip_runtime.h>

#define CROP 14
#define MAXBS 64
#define NLVL 4
#define BDIM 4
#define NBOX 128
#define CCH 256
#define NSL (NLVL * BDIM * MAXBS)        // 1024 slots
#define NBLK (NSL * CROP)                // 14336 blocks
#define NXCD 8
#define CPX (NBLK / NXCD)                // 1792 (NBLK % 8 == 0 -> bijective swizzle)

typedef float f32x4 __attribute__((ext_vector_type(4)));

// Kernel A: per-batch rank scan -> slot_map + output1.
// grid = B (4), block = 256 (one thread per (lvl,slot) pair).
__global__ void roi_meta_kernel(const float* __restrict__ db,
                                int* __restrict__ slot_map,
                                float* __restrict__ out1) {
    int b = blockIdx.x;
    int t = threadIdx.x;            // 0..255 = lvl*64 + slot
    __shared__ int lvl_arr[NBOX];
    __shared__ int smap[NLVL * MAXBS];

    if (t < NBOX) {
        // ids are exact small floats 0.0..3.0
        lvl_arr[t] = (int)db[(b * NBOX + t) * 7 + 0];
    }
    smap[t] = -1;
    __syncthreads();

    if (t < NLVL) {
        int r = 0;
        for (int n = 0; n < NBOX; ++n) {
            if (lvl_arr[n] == t) {
                if (r < MAXBS) smap[t * MAXBS + r] = n;
                r++;  // rank keeps counting; >=64 dropped (dest==MAX_BS slot)
            }
        }
    }
    __syncthreads();

    int n = smap[t];
    int lvl = t >> 6;
    int slot = t & 63;
    slot_map[(lvl * BDIM + b) * MAXBS + slot] = n;

    // output1: [B, NLVL*MAXBS, 6], level-concatenated along axis 1
    float* o = out1 + ((size_t)(b * (NLVL * MAXBS) + t)) * 6;
    if (n >= 0) {
        const float* src = db + (b * NBOX + n) * 7 + 1;  // cx,cy,w,h,cls,conf
        #pragma unroll
        for (int j = 0; j < 6; ++j) o[j] = src[j];
    } else {
        #pragma unroll
        for (int j = 0; j < 6; ++j) o[j] = 0.f;
    }
}

// Kernel B: one block per (slot, y) output row.
// Threads: cq = t & 63 -> channel quad (float4 over 256 ch), xg = t >> 6 -> x stride group.
// XCD-bijective swizzle keeps all 14 y-rows of a slot on one XCD so the shared
// bilinear fmap rows (iy1 of row y == iy0 of row y+1) hit that XCD's L2.
__global__ __launch_bounds__(256) void roi_crop_kernel(
        const float* __restrict__ f0,
        const float* __restrict__ f1,
        const float* __restrict__ f2,
        const float* __restrict__ f3,
        const float* __restrict__ db,
        const int* __restrict__ slot_map,
        float* __restrict__ out0) {
    int orig = blockIdx.x;
    int wid  = (orig & (NXCD - 1)) * CPX + (orig >> 3);   // bijective: 14336 % 8 == 0
    int y  = wid % CROP;
    int sl = wid / CROP;            // lvl*256 + b*64 + slot, 0..1023
    int t  = threadIdx.x;
    int cq = t & 63;                // float4 channel index: channels [cq*4, cq*4+4)
    int xg = t >> 6;                // 0..3

    f32x4* out = (f32x4*)(out0 + ((size_t)(sl * CROP + y)) * CROP * CCH);
    // out element for (x, cq) = x*64 + cq

    int n = slot_map[sl];
    if (n < 0) {
        f32x4 z = {0.f, 0.f, 0.f, 0.f};
        #pragma unroll
        for (int x = xg; x < CROP; x += 4) out[x * 64 + cq] = z;
        return;
    }

    int lvl = sl >> 8;
    int b   = (sl >> 6) & 3;
    int s   = 256 >> lvl;           // fmap H == W
    const float* f = (lvl == 0) ? f0 : (lvl == 1) ? f1 : (lvl == 2) ? f2 : f3;

    const float* bx = db + (b * NBOX + n) * 7;
    float cx = bx[1], cy = bx[2], w = bx[3], h = bx[4];

    // normalized box, matching reference fp32 op order
    float y1n = (cy - h * 0.5f) / 1023.0f;
    float x1n = (cx - w * 0.5f) / 1023.0f;
    float y2n = (cy + h * 0.5f) / 1023.0f;
    float x2n = (cx + w * 0.5f) / 1023.0f;

    float Hm1 = (float)(s - 1);
    float ty = (float)y / 13.0f;
    float ys = y1n * Hm1 + ty * ((y2n - y1n) * Hm1);
    float y0f = floorf(ys);
    float wy = ys - y0f;
    int iy0 = (int)y0f;
    iy0 = iy0 < 0 ? 0 : (iy0 > s - 1 ? s - 1 : iy0);
    int iy1 = iy0 + 1;
    if (iy1 > s - 1) iy1 = s - 1;
    bool vy = (ys >= 0.f) && (ys <= Hm1);

    const f32x4* rowT = (const f32x4*)(f + ((size_t)(b * s + iy0)) * s * CCH);
    const f32x4* rowB = (const f32x4*)(f + ((size_t)(b * s + iy1)) * s * CCH);

    float x1nH   = x1n * Hm1;
    float xscale = (x2n - x1n) * Hm1;
    float omwy = 1.f - wy;

    #pragma unroll
    for (int x = xg; x < CROP; x += 4) {
        float xs = x1nH + ((float)x / 13.0f) * xscale;
        float x0f = floorf(xs);
        float wx = xs - x0f;
        int ix0 = (int)x0f;
        ix0 = ix0 < 0 ? 0 : (ix0 > s - 1 ? s - 1 : ix0);
        int ix1 = ix0 + 1;
        if (ix1 > s - 1) ix1 = s - 1;
        bool vx = (xs >= 0.f) && (xs <= Hm1);

        f32x4 a  = rowT[ix0 * 64 + cq];
        f32x4 bv = rowT[ix1 * 64 + cq];
        f32x4 cv = rowB[ix0 * 64 + cq];
        f32x4 dv = rowB[ix1 * 64 + cq];

        float omwx = 1.f - wx;
        f32x4 top = a  * omwx + bv * wx;
        f32x4 bot = cv * omwx + dv * wx;
        f32x4 v   = top * omwy + bot * wy;

        if (!(vy && vx)) v = (f32x4){0.f, 0.f, 0.f, 0.f};
        out[x * 64 + cq] = v;
    }
}

extern "C" void kernel_launch(void* const* d_in, const int* in_sizes, int n_in,
                              void* d_out, int out_size, void* d_ws, size_t ws_size,
                              hipStream_t stream) {
    const float* f0 = (const float*)d_in[0];
    const float* f1 = (const float*)d_in[1];
    const float* f2 = (const float*)d_in[2];
    const float* f3 = (const float*)d_in[3];
    const float* db = (const float*)d_in[4];
    // d_in[5] = images, only shapes (1024x1024) are used -> hardcoded

    float* out0 = (float*)d_out;
    float* out1 = out0 + (size_t)NSL * CROP * CROP * CCH;
    int* slot_map = (int*)d_ws;     // 4 KB

    roi_meta_kernel<<<BDIM, 256, 0, stream>>>(db, slot_map, out1);
    roi_crop_kernel<<<NBLK, 256, 0, stream>>>(
        f0, f1, f2, f3, db, slot_map, out0);
}

// Round 2
// 463.420 us; speedup vs baseline: 1.0282x; 1.0282x over previous
//
#include <hip/hip_runtime.h>

#define CROP 14
#define MAXBS 64
#define NLVL 4
#define BDIM 4
#define NBOX 128
#define CCH 256
#define NSL (NLVL * BDIM * MAXBS)        // 1024 slots
#define NBLK (NSL * CROP)                // 14336 blocks

typedef float f32x4 __attribute__((ext_vector_type(4)));

// Kernel A: per-batch rank scan -> slot_map + output1.
// grid = B (4), block = 256 (one thread per (lvl,slot) pair).
__global__ void roi_meta_kernel(const float* __restrict__ db,
                                int* __restrict__ slot_map,
                                float* __restrict__ out1) {
    int b = blockIdx.x;
    int t = threadIdx.x;            // 0..255 = lvl*64 + slot
    __shared__ int lvl_arr[NBOX];
    __shared__ int smap[NLVL * MAXBS];

    if (t < NBOX) {
        // ids are exact small floats 0.0..3.0
        lvl_arr[t] = (int)db[(b * NBOX + t) * 7 + 0];
    }
    smap[t] = -1;
    __syncthreads();

    if (t < NLVL) {
        int r = 0;
        for (int n = 0; n < NBOX; ++n) {
            if (lvl_arr[n] == t) {
                if (r < MAXBS) smap[t * MAXBS + r] = n;
                r++;  // rank keeps counting; >=64 dropped (dest==MAX_BS slot)
            }
        }
    }
    __syncthreads();

    int n = smap[t];
    int lvl = t >> 6;
    int slot = t & 63;
    slot_map[(lvl * BDIM + b) * MAXBS + slot] = n;

    // output1: [B, NLVL*MAXBS, 6], level-concatenated along axis 1
    float* o = out1 + ((size_t)(b * (NLVL * MAXBS) + t)) * 6;
    if (n >= 0) {
        const float* src = db + (b * NBOX + n) * 7 + 1;  // cx,cy,w,h,cls,conf
        #pragma unroll
        for (int j = 0; j < 6; ++j) o[j] = src[j];
    } else {
        #pragma unroll
        for (int j = 0; j < 6; ++j) o[j] = 0.f;
    }
}

// Kernel B: one block per (slot, y) output row.
// Threads: cq = t & 63 -> channel quad (float4 over 256 ch), xg = t >> 6 -> x stride group.
// Output is write-once streaming data: store non-temporally so the 205 MB of
// writes don't evict fmap read lines from L2/L3 (reads have ~2x reuse from
// shared bilinear neighbors).
__global__ __launch_bounds__(256) void roi_crop_kernel(
        const float* __restrict__ f0,
        const float* __restrict__ f1,
        const float* __restrict__ f2,
        const float* __restrict__ f3,
        const float* __restrict__ db,
        const int* __restrict__ slot_map,
        float* __restrict__ out0) {
    int bid = blockIdx.x;
    int y  = bid % CROP;
    int sl = bid / CROP;            // lvl*256 + b*64 + slot, 0..1023
    int t  = threadIdx.x;
    int cq = t & 63;                // float4 channel index: channels [cq*4, cq*4+4)
    int xg = t >> 6;                // 0..3

    f32x4* out = (f32x4*)(out0 + ((size_t)(sl * CROP + y)) * CROP * CCH);
    // out element for (x, cq) = x*64 + cq

    int n = slot_map[sl];
    if (n < 0) {
        f32x4 z = {0.f, 0.f, 0.f, 0.f};
        #pragma unroll
        for (int xi = 0; xi < 4; ++xi) {
            int x = xg + xi * 4;
            if (x < CROP) __builtin_nontemporal_store(z, &out[x * 64 + cq]);
        }
        return;
    }

    int lvl = sl >> 8;
    int b   = (sl >> 6) & 3;
    int s   = 256 >> lvl;           // fmap H == W
    const float* f = (lvl == 0) ? f0 : (lvl == 1) ? f1 : (lvl == 2) ? f2 : f3;

    const float* bx = db + (b * NBOX + n) * 7;
    float cx = bx[1], cy = bx[2], w = bx[3], h = bx[4];

    // normalized box, matching reference fp32 op order
    float y1n = (cy - h * 0.5f) / 1023.0f;
    float x1n = (cx - w * 0.5f) / 1023.0f;
    float y2n = (cy + h * 0.5f) / 1023.0f;
    float x2n = (cx + w * 0.5f) / 1023.0f;

    float Hm1 = (float)(s - 1);
    float ty = (float)y / 13.0f;
    float ys = y1n * Hm1 + ty * ((y2n - y1n) * Hm1);
    float y0f = floorf(ys);
    float wy = ys - y0f;
    int iy0 = (int)y0f;
    iy0 = iy0 < 0 ? 0 : (iy0 > s - 1 ? s - 1 : iy0);
    int iy1 = iy0 + 1;
    if (iy1 > s - 1) iy1 = s - 1;
    bool vy = (ys >= 0.f) && (ys <= Hm1);

    const f32x4* rowT = (const f32x4*)(f + ((size_t)(b * s + iy0)) * s * CCH);
    const f32x4* rowB = (const f32x4*)(f + ((size_t)(b * s + iy1)) * s * CCH);

    float x1nH   = x1n * Hm1;
    float xscale = (x2n - x1n) * Hm1;
    float omwy = 1.f - wy;

    #pragma unroll
    for (int xi = 0; xi < 4; ++xi) {
        int x = xg + xi * 4;
        if (x >= CROP) break;

        float xs = x1nH + ((float)x / 13.0f) * xscale;
        float x0f = floorf(xs);
        float wx = xs - x0f;
        int ix0 = (int)x0f;
        ix0 = ix0 < 0 ? 0 : (ix0 > s - 1 ? s - 1 : ix0);
        int ix1 = ix0 + 1;
        if (ix1 > s - 1) ix1 = s - 1;
        bool vx = (xs >= 0.f) && (xs <= Hm1);

        f32x4 a  = rowT[ix0 * 64 + cq];
        f32x4 bv = rowT[ix1 * 64 + cq];
        f32x4 cv = rowB[ix0 * 64 + cq];
        f32x4 dv = rowB[ix1 * 64 + cq];

        float omwx = 1.f - wx;
        f32x4 top = a  * omwx + bv * wx;
        f32x4 bot = cv * omwx + dv * wx;
        f32x4 v   = top * omwy + bot * wy;

        if (!(vy && vx)) v = (f32x4){0.f, 0.f, 0.f, 0.f};
        __builtin_nontemporal_store(v, &out[x * 64 + cq]);
    }
}

extern "C" void kernel_launch(void* const* d_in, const int* in_sizes, int n_in,
                              void* d_out, int out_size, void* d_ws, size_t ws_size,
                              hipStream_t stream) {
    const float* f0 = (const float*)d_in[0];
    const float* f1 = (const float*)d_in[1];
    const float* f2 = (const float*)d_in[2];
    const float* f3 = (const float*)d_in[3];
    const float* db = (const float*)d_in[4];
    // d_in[5] = images, only shapes (1024x1024) are used -> hardcoded

    float* out0 = (float*)d_out;
    float* out1 = out0 + (size_t)NSL * CROP * CROP * CCH;
    int* slot_map = (int*)d_ws;     // 4 KB

    roi_meta_kernel<<<BDIM, 256, 0, stream>>>(db, slot_map, out1);
    roi_crop_kernel<<<NBLK, 256, 0, stream>>>(
        f0, f1, f2, f3, db, slot_map, out0);
}